// Round 7
// baseline (21579.262 us; speedup 1.0000x reference)
//
#include <hip/hip_runtime.h>
#include <math.h>

#define T_LEN 1500
#define DM 256
#define DI 64
#define MEMN 10
#define SYNCD 528
#define VOC 15
#define RRES 8                      // resident f16x8 chunks (of 20) per column

typedef _Float16 f16;
typedef _Float16 f16x2 __attribute__((ext_vector_type(2)));
typedef _Float16 f16x8 __attribute__((ext_vector_type(8)));

#define FDOT2(a, b, c) __builtin_amdgcn_fdot2((a), (b), (c), false)

static __device__ __forceinline__ float dot8(f16x8 w, f16x8 q, float acc) {
  acc = FDOT2(__builtin_shufflevector(w, w, 0, 1), __builtin_shufflevector(q, q, 0, 1), acc);
  acc = FDOT2(__builtin_shufflevector(w, w, 2, 3), __builtin_shufflevector(q, q, 2, 3), acc);
  acc = FDOT2(__builtin_shufflevector(w, w, 4, 5), __builtin_shufflevector(q, q, 4, 5), acc);
  acc = FDOT2(__builtin_shufflevector(w, w, 6, 7), __builtin_shufflevector(q, q, 6, 7), acc);
  return acc;
}
static __device__ __forceinline__ f16x2 pack2(float a, float b) {
  f16x2 r; r.x = (_Float16)a; r.y = (_Float16)b; return r;
}
static __device__ __forceinline__ float sigm(float x) { return 1.0f / (1.0f + __expf(-x)); }

struct Params {
  const float *x, *st0, *ast0, *Wb, *bb, *Wf, *bf, *gf, *bef,
              *Wd, *bd, *gd, *bed, *Wu, *bu, *gu, *beu, *gs, *bes,
              *w1, *b1, *w2, *b2, *Wh, *bh;
  const f16* wf16;
  float* out;
};

struct Smem {
  float4 W1v[MEMN * DM];
  float4 W2v[DM];
  float4 B1v[DM];
  float2 B2v[DM];
  float Bf[2 * DM];
  float Bu[2 * DM];
  float Bd[32];
  float Gf[DM], Bef[DM], Gu[DM], Beu[DM], Gs[DM], Bes[DM];
  float Gd[16], Bed[16];
  float Bh[16];
  float Bb[DI];
  __attribute__((aligned(16))) float St[MEMN * DM];
  __attribute__((aligned(16))) float H0[DM];
  float Act[DM];
  __attribute__((aligned(16))) float D1[16];
  float X2[2][DI];
  __attribute__((aligned(16))) f16x2 Pre2[160];
  float PartD[16 * 33];
  float PartK[512];
  float PartH[240];
  float2 RedAB[8];
  float2 Red2AB[8];
  float Prod[SYNCD];
  float WhL[SYNCD * VOC];
  int Pair[SYNCD];
};

// Pre-kernel: Wf f32 [k][col] -> f16 chunk-major [k/8][col][k%8].
// A wave-load of chunk jg at consecutive cols is fully coalesced (16B/lane contiguous).
__global__ __launch_bounds__(512) void wf16_kernel(const float* __restrict__ Wf,
                                                   f16* __restrict__ out) {
  int k = blockIdx.x;          // 0..319
  int c = threadIdx.x;         // 0..511
  out[((size_t)(k >> 3) * 512 + (size_t)c) * 8 + (k & 7)] = (f16)Wf[(size_t)k * 512 + c];
}

__global__ __launch_bounds__(512)
void ctm_kernel(Params P) {
  const int tid = threadIdx.x;
  const int b = blockIdx.x;
  __shared__ Smem sm_s;
  Smem* sm = &sm_s;

  // ---------------- LDS preload (once) ----------------
  for (int i = tid; i < MEMN * DM; i += 512) sm->W1v[i] = ((const float4*)P.w1)[i];
  if (tid < DM) {
    float2 a = ((const float2*)P.w2)[tid];
    float2 c = ((const float2*)P.w2)[DM + tid];
    float4 w; w.x = a.x; w.y = a.y; w.z = c.x; w.w = c.y;
    sm->W2v[tid] = w;
    sm->B1v[tid] = ((const float4*)P.b1)[tid];
    sm->B2v[tid] = ((const float2*)P.b2)[tid];
    sm->Gf[tid] = P.gf[tid]; sm->Bef[tid] = P.bef[tid];
    sm->Gu[tid] = P.gu[tid]; sm->Beu[tid] = P.beu[tid];
    sm->Gs[tid] = P.gs[tid]; sm->Bes[tid] = P.bes[tid];
  }
  sm->Bf[tid] = P.bf[tid];
  sm->Bu[tid] = P.bu[tid];
  if (tid < 32) sm->Bd[tid] = P.bd[tid];
  if (tid < 16) { sm->Gd[tid] = P.gd[tid]; sm->Bed[tid] = P.bed[tid]; }
  if (tid < VOC) sm->Bh[tid] = P.bh[tid];
  if (tid < DI) sm->Bb[tid] = P.bb[tid];
  for (int i = tid; i < MEMN * DM; i += 512) {
    int m = i >> 8, d = i & 255;
    sm->St[m * DM + d] = P.st0[d * MEMN + m];
  }
  if (tid < DI) sm->X2[0][tid] = P.x[(size_t)b * T_LEN * DI + tid];
  for (int i = tid; i < SYNCD * VOC; i += 512) sm->WhL[i] = P.Wh[i];
  for (int pp = tid; pp < SYNCD; pp += 512) {
    int i = 0, cum = 0;
    while (pp >= cum + (32 - i)) { cum += 32 - i; ++i; }
    sm->Pair[pp] = (i << 8) | (i + (pp - cum));
  }

  // ---------------- register weights ----------------
  const int p = tid & 1;         // K-half
  const int ch = tid >> 1;       // owned channel 0..255 (cols ch, ch+256)
  const f16x8* wbase = (const f16x8*)P.wf16;   // [jg*512 + col]
  const int jg0 = p * 20;
  f16x8 wra[RRES], wrb[RRES];
  #pragma unroll
  for (int j = 0; j < RRES; ++j) {
    wra[j] = wbase[(size_t)(jg0 + j) * 512 + ch];
    wrb[j] = wbase[(size_t)(jg0 + j) * 512 + ch + 256];
  }

  const int jD = tid & 31, kcD = tid >> 5;   // Wd mapping
  f16x8 wd8[2];
  #pragma unroll
  for (int h2 = 0; h2 < 2; ++h2) {
    f16x8 t;
    #pragma unroll
    for (int e = 0; e < 8; ++e) t[e] = (f16)P.Wd[(kcD * 16 + h2 * 8 + e) * 32 + jD];
    wd8[h2] = t;
  }
  f16x8 wua8, wub8;
  {
    f16x8 t, t2;
    #pragma unroll
    for (int e = 0; e < 8; ++e) {
      t[e]  = (f16)P.Wu[(p * 8 + e) * 512 + ch];
      t2[e] = (f16)P.Wu[(p * 8 + e) * 512 + ch + 256];
    }
    wua8 = t; wub8 = t2;
  }
  const int jK = tid & 63, kcK = tid >> 6;   // Wb mapping
  f16x8 wbr8;
  {
    f16x8 t;
    #pragma unroll
    for (int e = 0; e < 8; ++e) t[e] = (f16)P.Wb[(kcK * 8 + e) * 64 + jK];
    wbr8 = t;
  }

  __syncthreads();

  // ---------------- prologue: kv(t=0) + initial act pack ----------------
  {
    float s = 0.f;
    #pragma unroll
    for (int e = 0; e < 8; ++e) s += sm->X2[0][kcK * 8 + e] * (float)wbr8[e];
    sm->PartK[kcK * 64 + jK] = s;
    if ((tid & 3) == 0) {
      int e = tid >> 2;
      float a0 = P.ast0[(2 * e) * MEMN + (MEMN - 1)];
      float a1 = P.ast0[(2 * e + 1) * MEMN + (MEMN - 1)];
      sm->Pre2[32 + e] = pack2(a0, a1);
    }
  }
  __syncthreads();
  if (tid >= 256 && tid < 320) {
    int j = tid - 256;
    float kv = sm->Bb[j];
    #pragma unroll
    for (int kc = 0; kc < 8; ++kc) kv += sm->PartK[kc * 64 + j];
    kv = fmaxf(kv, 0.f);
    float kn = __shfl_xor(kv, 1);
    if ((j & 1) == 0) sm->Pre2[j >> 1] = pack2(kv, kn);
  }
  __syncthreads();

  int head = 0;
  for (int t = 0; t < T_LEN; ++t) {
    float xr = 0.f;
    if (tid < DI && t + 1 < T_LEN) xr = P.x[((size_t)b * T_LEN + (t + 1)) * DI + tid];

    for (int it = 0; it < 2; ++it) {
      // ---- P1: Wf GEMV: streamed chunks (issued first, coalesced) + resident regs ----
      if (it == 1 && tid < DI) sm->X2[(t + 1) & 1][tid] = xr;
      const f16x8* pr8 = ((const f16x8*)sm->Pre2) + p * 20;
      float aA0 = 0.f, aB0 = 0.f, aA1 = 0.f, aB1 = 0.f;
      {
        // anti-hoist: keep the streamed loads inside this iteration
        unsigned long long ub_ = (unsigned long long)(wbase + (size_t)(jg0 + RRES) * 512);
        asm volatile("" : "+v"(ub_));
        const f16x8* ws = (const f16x8*)ub_;   // ws[(j)*512 + col]
        #pragma unroll
        for (int j = 0; j < 20 - RRES; ++j) {
          f16x8 qa = ws[(size_t)j * 512 + ch];
          f16x8 qb = ws[(size_t)j * 512 + ch + 256];
          f16x8 qq = pr8[RRES + j];
          aA1 = dot8(qa, qq, aA1);
          aB1 = dot8(qb, qq, aB1);
        }
      }
      #pragma unroll
      for (int j = 0; j < RRES; ++j) {
        f16x8 qq = pr8[j];
        aA0 = dot8(wra[j], qq, aA0);
        aB0 = dot8(wrb[j], qq, aB0);
      }
      float av = aA0 + aA1, bv = aB0 + aB1;
      av += __shfl_xor(av, 1); bv += __shfl_xor(bv, 1);
      av += sm->Bf[ch]; bv += sm->Bf[DM + ch];
      float g = av * sigm(bv);
      float s1 = g, s2 = g * g;
      #pragma unroll
      for (int m = 1; m < 64; m <<= 1) { s1 += __shfl_xor(s1, m); s2 += __shfl_xor(s2, m); }
      if ((tid & 63) == 0) { float2 r; r.x = s1; r.y = s2; sm->RedAB[tid >> 6] = r; }
      __syncthreads();  // B1

      // ---- P2: h0 = LN(g) ----
      float S1 = 0.f, S2 = 0.f;
      #pragma unroll
      for (int w = 0; w < 8; ++w) { float2 r = sm->RedAB[w]; S1 += r.x; S2 += r.y; }
      float mean = S1 * (1.0f / 512.0f);
      float var = S2 * (1.0f / 512.0f) - mean * mean;
      float h0v = (g - mean) * rsqrtf(var + 1e-5f) * sm->Gf[ch] + sm->Bef[ch];
      if (!p) sm->H0[ch] = h0v;
      __syncthreads();  // B2

      // ---- P3: Wd partials ----
      {
        float s = 0.f;
        #pragma unroll
        for (int qq = 0; qq < 4; ++qq) {
          float4 hv = ((const float4*)sm->H0)[kcD * 4 + qq];
          s += (float)wd8[qq >> 1][(qq & 1) * 4 + 0] * hv.x
             + (float)wd8[qq >> 1][(qq & 1) * 4 + 1] * hv.y
             + (float)wd8[qq >> 1][(qq & 1) * 4 + 2] * hv.z
             + (float)wd8[qq >> 1][(qq & 1) * 4 + 3] * hv.w;
        }
        sm->PartD[kcD * 33 + jD] = s;
      }
      __syncthreads();  // B3

      // ---- P4: d1 = LN(GLU(Wd out)) ----
      if (tid < 32) {
        int j = tid & 15;
        int half = tid >> 4;
        float s = 0.f;
        #pragma unroll
        for (int kc = 0; kc < 16; ++kc) s += sm->PartD[kc * 33 + half * 16 + j];
        float oth = __shfl_xor(s, 16);
        float gg = (s + sm->Bd[j]) * sigm(oth + sm->Bd[16 + j]);
        float t1 = gg, t2 = gg * gg;
        #pragma unroll
        for (int m = 1; m < 16; m <<= 1) { t1 += __shfl_xor(t1, m); t2 += __shfl_xor(t2, m); }
        float mn = t1 * (1.0f / 16.0f), vr = t2 * (1.0f / 16.0f) - mn * mn;
        float d1 = (gg - mn) * rsqrtf(vr + 1e-5f) * sm->Gd[j] + sm->Bed[j];
        if (tid < 16) sm->D1[j] = d1;
      }
      __syncthreads();  // B4

      // ---- P5: Wu + GLU + wave-reduce ----
      float gu;
      {
        const float4* d4 = (const float4*)sm->D1;
        float4 dl = d4[p * 2], dh = d4[p * 2 + 1];
        float ua = (float)wua8[0] * dl.x + (float)wua8[1] * dl.y
                 + (float)wua8[2] * dl.z + (float)wua8[3] * dl.w
                 + (float)wua8[4] * dh.x + (float)wua8[5] * dh.y
                 + (float)wua8[6] * dh.z + (float)wua8[7] * dh.w;
        float ub = (float)wub8[0] * dl.x + (float)wub8[1] * dl.y
                 + (float)wub8[2] * dl.z + (float)wub8[3] * dl.w
                 + (float)wub8[4] * dh.x + (float)wub8[5] * dh.y
                 + (float)wub8[6] * dh.z + (float)wub8[7] * dh.w;
        ua += __shfl_xor(ua, 1); ub += __shfl_xor(ub, 1);
        ua += sm->Bu[ch]; ub += sm->Bu[DM + ch];
        gu = ua * sigm(ub);
        float t1 = gu, t2 = gu * gu;
        #pragma unroll
        for (int m = 1; m < 64; m <<= 1) { t1 += __shfl_xor(t1, m); t2 += __shfl_xor(t2, m); }
        if ((tid & 63) == 0) { float2 r; r.x = t1; r.y = t2; sm->RedAB[tid >> 6] = r; }
      }
      __syncthreads();  // B5

      // ---- P6: u0 = LN(gu); x2 = u0 + h0; reduce for state-LN ----
      float x2v;
      {
        float U1 = 0.f, U2 = 0.f;
        #pragma unroll
        for (int w = 0; w < 8; ++w) { float2 r = sm->RedAB[w]; U1 += r.x; U2 += r.y; }
        float mn = U1 * (1.0f / 512.0f), vr = U2 * (1.0f / 512.0f) - mn * mn;
        float u0 = (gu - mn) * rsqrtf(vr + 1e-5f) * sm->Gu[ch] + sm->Beu[ch];
        x2v = u0 + h0v;
        float t1 = x2v, t2 = x2v * x2v;
        #pragma unroll
        for (int m = 1; m < 64; m <<= 1) { t1 += __shfl_xor(t1, m); t2 += __shfl_xor(t2, m); }
        if ((tid & 63) == 0) { float2 r; r.x = t1; r.y = t2; sm->Red2AB[tid >> 6] = r; }
      }
      __syncthreads();  // B6

      // ---- P7: state = LN(x2); trace update; nlm -> act; pack pre ----
      {
        float V1 = 0.f, V2 = 0.f;
        #pragma unroll
        for (int w = 0; w < 8; ++w) { float2 r = sm->Red2AB[w]; V1 += r.x; V2 += r.y; }
        float mn = V1 * (1.0f / 512.0f), vr = V2 * (1.0f / 512.0f) - mn * mn;
        float state = (x2v - mn) * rsqrtf(vr + 1e-5f) * sm->Gs[ch] + sm->Bes[ch];
        if (!p) sm->St[head * DM + ch] = state;
        float4 h1 = sm->B1v[ch];
        int base = head + 1; if (base >= MEMN) base -= MEMN;
        #pragma unroll
        for (int m = 0; m < MEMN - 1; ++m) {
          int slot = base + m; if (slot >= MEMN) slot -= MEMN;
          float tr = sm->St[slot * DM + ch];
          float4 wv = sm->W1v[m * DM + ch];
          h1.x += tr * wv.x; h1.y += tr * wv.y; h1.z += tr * wv.z; h1.w += tr * wv.w;
        }
        {
          float4 wv = sm->W1v[(MEMN - 1) * DM + ch];
          h1.x += state * wv.x; h1.y += state * wv.y; h1.z += state * wv.z; h1.w += state * wv.w;
        }
        float g0 = h1.x * sigm(h1.z), g1 = h1.y * sigm(h1.w);
        float4 w2v = sm->W2v[ch];
        float2 b2v = sm->B2v[ch];
        float o0 = g0 * w2v.x + g1 * w2v.z + b2v.x;
        float o1 = g0 * w2v.y + g1 * w2v.w + b2v.y;
        float act = o0 * sigm(o1);
        if (!p) sm->Act[ch] = act;
        float an = __shfl_xor(act, 2);
        if ((tid & 3) == 0) sm->Pre2[32 + (tid >> 2)] = pack2(act, an);
        head += 1; if (head >= MEMN) head = 0;
      }
      __syncthreads();  // B7
    }  // it

    // ---- S1: sync products + next-step Wb partials + store logits(t-1) ----
    {
      int pr = sm->Pair[tid];
      sm->Prod[tid] = sm->Act[pr >> 8] * sm->Act[pr & 255];
      if (tid < SYNCD - 512) {
        int pr2 = sm->Pair[512 + tid];
        sm->Prod[512 + tid] = sm->Act[pr2 >> 8] * sm->Act[pr2 & 255];
      }
      const float* X = sm->X2[(t + 1) & 1];
      float s = 0.f;
      #pragma unroll
      for (int e = 0; e < 8; ++e) s += X[kcK * 8 + e] * (float)wbr8[e];
      sm->PartK[kcK * 64 + jK] = s;
      if (t > 0 && tid < VOC) {
        float o = sm->Bh[tid];
        #pragma unroll
        for (int kc2 = 0; kc2 < 16; ++kc2) o += sm->PartH[kc2 * 15 + tid];
        P.out[((size_t)b * T_LEN + (t - 1)) * VOC + tid] = o;
      }
    }
    __syncthreads();  // B8

    // ---- S2: Wh partials + kv reduce/pack for t+1 ----
    if (tid < 240) {
      int kc = (tid * 4370) >> 16;
      int v = tid - kc * 15;
      float s = 0.f;
      #pragma unroll
      for (int e = 0; e < 33; ++e) {
        int pp = kc * 33 + e;
        s += sm->Prod[pp] * sm->WhL[pp * 15 + v];
      }
      sm->PartH[kc * 15 + v] = s;
    } else if (tid >= 256 && tid < 320) {
      int j = tid - 256;
      float kv = sm->Bb[j];
      #pragma unroll
      for (int kc = 0; kc < 8; ++kc) kv += sm->PartK[kc * 64 + j];
      kv = fmaxf(kv, 0.f);
      float kn = __shfl_xor(kv, 1);
      if ((j & 1) == 0) sm->Pre2[j >> 1] = pack2(kv, kn);
    }
    __syncthreads();  // B9
  }  // t

  if (tid < VOC) {
    float o = sm->Bh[tid];
    #pragma unroll
    for (int kc = 0; kc < 16; ++kc) o += sm->PartH[kc * 15 + tid];
    P.out[((size_t)b * T_LEN + (T_LEN - 1)) * VOC + tid] = o;
  }
}

extern "C" void kernel_launch(void* const* d_in, const int* in_sizes, int n_in,
                              void* d_out, int out_size, void* d_ws, size_t ws_size,
                              hipStream_t stream) {
  (void)n_in; (void)out_size; (void)ws_size;
  Params P;
  P.x   = (const float*)d_in[0];
  P.st0 = (const float*)d_in[1];
  P.ast0= (const float*)d_in[2];
  P.Wb  = (const float*)d_in[3];
  P.bb  = (const float*)d_in[4];
  P.Wf  = (const float*)d_in[5];
  P.bf  = (const float*)d_in[6];
  P.gf  = (const float*)d_in[7];
  P.bef = (const float*)d_in[8];
  P.Wd  = (const float*)d_in[9];
  P.bd  = (const float*)d_in[10];
  P.gd  = (const float*)d_in[11];
  P.bed = (const float*)d_in[12];
  P.Wu  = (const float*)d_in[13];
  P.bu  = (const float*)d_in[14];
  P.gu  = (const float*)d_in[15];
  P.beu = (const float*)d_in[16];
  P.gs  = (const float*)d_in[17];
  P.bes = (const float*)d_in[18];
  P.w1  = (const float*)d_in[19];
  P.b1  = (const float*)d_in[20];
  P.w2  = (const float*)d_in[21];
  P.b2  = (const float*)d_in[22];
  P.Wh  = (const float*)d_in[23];
  P.bh  = (const float*)d_in[24];
  P.out = (float*)d_out;

  f16* wf16 = (f16*)d_ws;
  hipLaunchKernelGGL(wf16_kernel, dim3(320), dim3(512), 0, stream, P.Wf, wf16);
  P.wf16 = wf16;

  int B = in_sizes[0] / (T_LEN * DI);
  hipLaunchKernelGGL(ctm_kernel, dim3(B), dim3(512), 0, stream, P);
}

// Round 8
// 18408.693 us; speedup vs baseline: 1.1722x; 1.1722x over previous
//
#include <hip/hip_runtime.h>
#include <math.h>

#define T_LEN 1500
#define DM 256
#define DI 64
#define MEMN 10
#define SYNCD 528
#define VOC 15

typedef _Float16 f16;
typedef _Float16 f16x2 __attribute__((ext_vector_type(2)));
typedef _Float16 f16x4 __attribute__((ext_vector_type(4)));
typedef _Float16 f16x8 __attribute__((ext_vector_type(8)));

#define FDOT2(a, b, c) __builtin_amdgcn_fdot2((a), (b), (c), false)

static __device__ __forceinline__ float dot8(f16x8 w, f16x8 q, float acc) {
  acc = FDOT2(__builtin_shufflevector(w, w, 0, 1), __builtin_shufflevector(q, q, 0, 1), acc);
  acc = FDOT2(__builtin_shufflevector(w, w, 2, 3), __builtin_shufflevector(q, q, 2, 3), acc);
  acc = FDOT2(__builtin_shufflevector(w, w, 4, 5), __builtin_shufflevector(q, q, 4, 5), acc);
  acc = FDOT2(__builtin_shufflevector(w, w, 6, 7), __builtin_shufflevector(q, q, 6, 7), acc);
  return acc;
}
static __device__ __forceinline__ f16x2 pack2(float a, float b) {
  f16x2 r; r.x = (_Float16)a; r.y = (_Float16)b; return r;
}
static __device__ __forceinline__ float sigm(float x) { return 1.0f / (1.0f + __expf(-x)); }

struct Params {
  const float *x, *st0, *ast0, *Wb, *bb, *Wf, *bf, *gf, *bef,
              *Wd, *bd, *gd, *bed, *Wu, *bu, *gu, *beu, *gs, *bes,
              *w1, *b1, *w2, *b2, *Wh, *bh;
  const f16* wf16;
  float* out;
};

struct Smem {
  __attribute__((aligned(16))) char dbuf[3 * 16384];  // stream ring: 3 slots x (2 halves x 8KB)
  f16x4 W1h[MEMN * DM];         // w1[m][d][0..3] as f16
  float4 W2v[DM];
  float4 B1v[DM];
  float2 B2v[DM];
  float Bf[2 * DM];
  float Bu[2 * DM];
  float Bd[32];
  float Gf[DM], Bef[DM], Gu[DM], Beu[DM], Gs[DM], Bes[DM];
  float Gd[16], Bed[16];
  float Bh[16];
  float Bb[DI];
  __attribute__((aligned(16))) float St[MEMN * DM];
  __attribute__((aligned(16))) float H0[DM];
  float Act[DM];
  __attribute__((aligned(16))) float D1[16];
  float X2[2][DI];
  __attribute__((aligned(16))) f16x2 Pre2[160];       // = f16x8[40] K-chunks
  float PartD[16 * 33];
  float PartK[512];
  float PartH[240];
  float2 RedAB[8];
  float2 Red2AB[8];
  float Prod[SYNCD];
  float WhL[SYNCD * VOC];
  int Pair[SYNCD];
};

// Wf f32 [k][col] -> f16 plane-major [k/8][col][k%8]; plane = 512 cols x 16B = 8KB.
__global__ __launch_bounds__(512) void wf16_kernel(const float* __restrict__ Wf,
                                                   f16* __restrict__ out) {
  int k = blockIdx.x;          // 0..319
  int c = threadIdx.x;         // 0..511
  out[((size_t)(k >> 3) * 512 + (size_t)c) * 8 + (k & 7)] = (f16)Wf[(size_t)k * 512 + c];
}

#define FOR8(X) X(0) X(1) X(2) X(3) X(4) X(5) X(6) X(7)
#define DECLR(i) f16x8 wr_a##i, wr_b##i;
#define LOADR(i) wr_a##i = wf8[(size_t)(p20 + (i)) * 512 + ch]; \
                 wr_b##i = wf8[(size_t)(p20 + (i)) * 512 + ch + 256];
#define DOTR(i) { f16x8 q_ = pr8[i]; accA = dot8(wr_a##i, q_, accA); accB = dot8(wr_b##i, q_, accB); }

// Issue one stage: 2 global_load_lds (one per K-half plane), wave-slot LDS dest.
#define STAGE(s) do { \
  int lo_ = __builtin_amdgcn_readfirstlane(((s) % 3) * 16384 + woff); \
  __builtin_amdgcn_global_load_lds( \
    (const __attribute__((address_space(1))) void*)(wfc + (size_t)(8 + (s)) * 8192 + gcoloff), \
    (__attribute__((address_space(3))) void*)(dbufc + lo_), 16, 0, 0); \
  __builtin_amdgcn_global_load_lds( \
    (const __attribute__((address_space(1))) void*)(wfc + (size_t)(28 + (s)) * 8192 + gcoloff), \
    (__attribute__((address_space(3))) void*)(dbufc + lo_ + 8192), 16, 0, 0); \
} while (0)

#define CONSUME(s, WAITSTR) do { \
  asm volatile(WAITSTR ::: "memory"); \
  __builtin_amdgcn_sched_barrier(0); \
  const f16x8* wsl_ = (const f16x8*)(dbufc + ((s) % 3) * 16384 + p * 8192 + woff); \
  f16x8 wa_ = wsl_[lhalf]; \
  f16x8 wb_ = wsl_[32 + lhalf]; \
  asm volatile("s_waitcnt lgkmcnt(0)" ::: "memory"); \
  __builtin_amdgcn_sched_barrier(0); \
  if ((s) + 3 < 12) STAGE((s) + 3); \
  f16x8 q_ = pr8[8 + (s)]; \
  accA = dot8(wa_, q_, accA); \
  accB = dot8(wb_, q_, accB); \
} while (0)

__global__ __launch_bounds__(512)
void ctm_kernel(Params P) {
  const int tid = threadIdx.x;
  const int b = blockIdx.x;
  __shared__ Smem sm_s;
  Smem* sm = &sm_s;

  // ---------------- LDS preload (once) ----------------
  for (int i = tid; i < MEMN * DM; i += 512) {
    float4 v = ((const float4*)P.w1)[i];
    f16x4 t; t[0] = (f16)v.x; t[1] = (f16)v.y; t[2] = (f16)v.z; t[3] = (f16)v.w;
    sm->W1h[i] = t;
  }
  if (tid < DM) {
    float2 a = ((const float2*)P.w2)[tid];
    float2 c = ((const float2*)P.w2)[DM + tid];
    float4 w; w.x = a.x; w.y = a.y; w.z = c.x; w.w = c.y;
    sm->W2v[tid] = w;
    sm->B1v[tid] = ((const float4*)P.b1)[tid];
    sm->B2v[tid] = ((const float2*)P.b2)[tid];
    sm->Gf[tid] = P.gf[tid]; sm->Bef[tid] = P.bef[tid];
    sm->Gu[tid] = P.gu[tid]; sm->Beu[tid] = P.beu[tid];
    sm->Gs[tid] = P.gs[tid]; sm->Bes[tid] = P.bes[tid];
  }
  sm->Bf[tid] = P.bf[tid];
  sm->Bu[tid] = P.bu[tid];
  if (tid < 32) sm->Bd[tid] = P.bd[tid];
  if (tid < 16) { sm->Gd[tid] = P.gd[tid]; sm->Bed[tid] = P.bed[tid]; }
  if (tid < VOC) sm->Bh[tid] = P.bh[tid];
  if (tid < DI) sm->Bb[tid] = P.bb[tid];
  for (int i = tid; i < MEMN * DM; i += 512) {
    int m = i >> 8, d = i & 255;
    sm->St[m * DM + d] = P.st0[d * MEMN + m];
  }
  if (tid < DI) sm->X2[0][tid] = P.x[(size_t)b * T_LEN * DI + tid];
  for (int i = tid; i < SYNCD * VOC; i += 512) sm->WhL[i] = P.Wh[i];
  for (int pp = tid; pp < SYNCD; pp += 512) {
    int i = 0, cum = 0;
    while (pp >= cum + (32 - i)) { cum += 32 - i; ++i; }
    sm->Pair[pp] = (i << 8) | (i + (pp - cum));
  }

  // ---------------- register weights ----------------
  const int p = tid & 1;                 // K-half
  const int ch = tid >> 1;               // channel 0..255 (cols ch, ch+256)
  const int p20 = p * 20;
  const int lane = tid & 63;
  const int lhalf = lane >> 1;
  const int woff = (tid >> 6) * 1024;    // wave's 1KB slice within a plane
  const char* wfc = (const char*)P.wf16;
  char* dbufc = (char*)sm->dbuf;
  // per-lane global column for streaming: lanes 0..31 -> a-cols, 32..63 -> b-cols
  const int gcol = (lane < 32) ? ((tid >> 6) * 32 + lane) : (256 + (tid >> 6) * 32 + (lane - 32));
  const int gcoloff = gcol * 16;

  const f16x8* wf8 = (const f16x8*)P.wf16;
  FOR8(DECLR)
  FOR8(LOADR)

  const int jD = tid & 31, kcD = tid >> 5;   // Wd mapping
  f16x8 wd8[2];
  #pragma unroll
  for (int h2 = 0; h2 < 2; ++h2) {
    f16x8 t;
    #pragma unroll
    for (int e = 0; e < 8; ++e) t[e] = (f16)P.Wd[(kcD * 16 + h2 * 8 + e) * 32 + jD];
    wd8[h2] = t;
  }
  f16x8 wua8, wub8;
  {
    f16x8 t, t2;
    #pragma unroll
    for (int e = 0; e < 8; ++e) {
      t[e]  = (f16)P.Wu[(p * 8 + e) * 512 + ch];
      t2[e] = (f16)P.Wu[(p * 8 + e) * 512 + ch + 256];
    }
    wua8 = t; wub8 = t2;
  }
  const int jK = tid & 63, kcK = tid >> 6;   // Wb mapping
  f16x8 wbr8;
  {
    f16x8 t;
    #pragma unroll
    for (int e = 0; e < 8; ++e) t[e] = (f16)P.Wb[(kcK * 8 + e) * 64 + jK];
    wbr8 = t;
  }

  __syncthreads();

  // ---------------- prologue: kv(t=0) + initial act pack ----------------
  {
    float s = 0.f;
    #pragma unroll
    for (int e = 0; e < 8; ++e) s += sm->X2[0][kcK * 8 + e] * (float)wbr8[e];
    sm->PartK[kcK * 64 + jK] = s;
    if ((tid & 3) == 0) {
      int e = tid >> 2;
      float a0 = P.ast0[(2 * e) * MEMN + (MEMN - 1)];
      float a1 = P.ast0[(2 * e + 1) * MEMN + (MEMN - 1)];
      sm->Pre2[32 + e] = pack2(a0, a1);
    }
  }
  __syncthreads();
  if (tid >= 256 && tid < 320) {
    int j = tid - 256;
    float kv = sm->Bb[j];
    #pragma unroll
    for (int kc = 0; kc < 8; ++kc) kv += sm->PartK[kc * 64 + j];
    kv = fmaxf(kv, 0.f);
    float kn = __shfl_xor(kv, 1);
    if ((j & 1) == 0) sm->Pre2[j >> 1] = pack2(kv, kn);
  }
  __syncthreads();

  int head = 0;
  float xr = 0.f;
  for (int t = 0; t < T_LEN; ++t) {
    for (int it = 0; it < 2; ++it) {
      // ---- P1: Wf GEMV = 8 resident chunks + 12 LDS-streamed chunks (3-deep pipeline) ----
      if (it == 1 && tid < DI) sm->X2[(t + 1) & 1][tid] = xr;   // commit prefetched x
      asm volatile("s_waitcnt vmcnt(0)" ::: "memory");          // isolate vmcnt pipeline
      STAGE(0); STAGE(1); STAGE(2);
      const f16x8* pr8 = ((const f16x8*)sm->Pre2) + p20;
      float accA = 0.f, accB = 0.f;
      FOR8(DOTR)
      CONSUME(0, "s_waitcnt vmcnt(4)");
      CONSUME(1, "s_waitcnt vmcnt(4)");
      CONSUME(2, "s_waitcnt vmcnt(4)");
      CONSUME(3, "s_waitcnt vmcnt(4)");
      CONSUME(4, "s_waitcnt vmcnt(4)");
      CONSUME(5, "s_waitcnt vmcnt(4)");
      CONSUME(6, "s_waitcnt vmcnt(4)");
      CONSUME(7, "s_waitcnt vmcnt(4)");
      CONSUME(8, "s_waitcnt vmcnt(4)");
      CONSUME(9, "s_waitcnt vmcnt(4)");
      CONSUME(10, "s_waitcnt vmcnt(2)");
      CONSUME(11, "s_waitcnt vmcnt(0)");
      float av = accA, bv = accB;
      av += __shfl_xor(av, 1); bv += __shfl_xor(bv, 1);
      av += sm->Bf[ch]; bv += sm->Bf[DM + ch];
      float g = av * sigm(bv);
      float s1 = g, s2 = g * g;
      #pragma unroll
      for (int m = 1; m < 64; m <<= 1) { s1 += __shfl_xor(s1, m); s2 += __shfl_xor(s2, m); }
      if ((tid & 63) == 0) { float2 r; r.x = s1; r.y = s2; sm->RedAB[tid >> 6] = r; }
      __syncthreads();  // B1

      // ---- P2: h0 = LN(g) (+ x prefetch for next step) ----
      if (it == 0 && tid < DI && t + 1 < T_LEN)
        xr = P.x[((size_t)b * T_LEN + (t + 1)) * DI + tid];
      float S1 = 0.f, S2 = 0.f;
      #pragma unroll
      for (int w = 0; w < 8; ++w) { float2 r = sm->RedAB[w]; S1 += r.x; S2 += r.y; }
      float mean = S1 * (1.0f / 512.0f);
      float var = S2 * (1.0f / 512.0f) - mean * mean;
      float h0v = (g - mean) * rsqrtf(var + 1e-5f) * sm->Gf[ch] + sm->Bef[ch];
      if (!p) sm->H0[ch] = h0v;
      __syncthreads();  // B2

      // ---- P3: Wd partials ----
      {
        float s = 0.f;
        #pragma unroll
        for (int qq = 0; qq < 4; ++qq) {
          float4 hv = ((const float4*)sm->H0)[kcD * 4 + qq];
          s += (float)wd8[qq >> 1][(qq & 1) * 4 + 0] * hv.x
             + (float)wd8[qq >> 1][(qq & 1) * 4 + 1] * hv.y
             + (float)wd8[qq >> 1][(qq & 1) * 4 + 2] * hv.z
             + (float)wd8[qq >> 1][(qq & 1) * 4 + 3] * hv.w;
        }
        sm->PartD[kcD * 33 + jD] = s;
      }
      __syncthreads();  // B3

      // ---- P4: d1 = LN(GLU(Wd out)) ----
      if (tid < 32) {
        int j = tid & 15;
        int half = tid >> 4;
        float s = 0.f;
        #pragma unroll
        for (int kc = 0; kc < 16; ++kc) s += sm->PartD[kc * 33 + half * 16 + j];
        float oth = __shfl_xor(s, 16);
        float gg = (s + sm->Bd[j]) * sigm(oth + sm->Bd[16 + j]);
        float t1 = gg, t2 = gg * gg;
        #pragma unroll
        for (int m = 1; m < 16; m <<= 1) { t1 += __shfl_xor(t1, m); t2 += __shfl_xor(t2, m); }
        float mn = t1 * (1.0f / 16.0f), vr = t2 * (1.0f / 16.0f) - mn * mn;
        float d1 = (gg - mn) * rsqrtf(vr + 1e-5f) * sm->Gd[j] + sm->Bed[j];
        if (tid < 16) sm->D1[j] = d1;
      }
      __syncthreads();  // B4

      // ---- P5: Wu + GLU + wave-reduce ----
      float gu;
      {
        const float4* d4 = (const float4*)sm->D1;
        float4 dl = d4[p * 2], dh = d4[p * 2 + 1];
        float ua = (float)wua8[0] * dl.x + (float)wua8[1] * dl.y
                 + (float)wua8[2] * dl.z + (float)wua8[3] * dl.w
                 + (float)wua8[4] * dh.x + (float)wua8[5] * dh.y
                 + (float)wua8[6] * dh.z + (float)wua8[7] * dh.w;
        float ub = (float)wub8[0] * dl.x + (float)wub8[1] * dl.y
                 + (float)wub8[2] * dl.z + (float)wub8[3] * dl.w
                 + (float)wub8[4] * dh.x + (float)wub8[5] * dh.y
                 + (float)wub8[6] * dh.z + (float)wub8[7] * dh.w;
        ua += __shfl_xor(ua, 1); ub += __shfl_xor(ub, 1);
        ua += sm->Bu[ch]; ub += sm->Bu[DM + ch];
        gu = ua * sigm(ub);
        float t1 = gu, t2 = gu * gu;
        #pragma unroll
        for (int m = 1; m < 64; m <<= 1) { t1 += __shfl_xor(t1, m); t2 += __shfl_xor(t2, m); }
        if ((tid & 63) == 0) { float2 r; r.x = t1; r.y = t2; sm->RedAB[tid >> 6] = r; }
      }
      __syncthreads();  // B5

      // ---- P6: u0 = LN(gu); x2 = u0 + h0; reduce for state-LN ----
      float x2v;
      {
        float U1 = 0.f, U2 = 0.f;
        #pragma unroll
        for (int w = 0; w < 8; ++w) { float2 r = sm->RedAB[w]; U1 += r.x; U2 += r.y; }
        float mn = U1 * (1.0f / 512.0f), vr = U2 * (1.0f / 512.0f) - mn * mn;
        float u0 = (gu - mn) * rsqrtf(vr + 1e-5f) * sm->Gu[ch] + sm->Beu[ch];
        x2v = u0 + h0v;
        float t1 = x2v, t2 = x2v * x2v;
        #pragma unroll
        for (int m = 1; m < 64; m <<= 1) { t1 += __shfl_xor(t1, m); t2 += __shfl_xor(t2, m); }
        if ((tid & 63) == 0) { float2 r; r.x = t1; r.y = t2; sm->Red2AB[tid >> 6] = r; }
      }
      __syncthreads();  // B6

      // ---- P7: state = LN(x2); trace update; nlm -> act; pack pre ----
      {
        float V1 = 0.f, V2 = 0.f;
        #pragma unroll
        for (int w = 0; w < 8; ++w) { float2 r = sm->Red2AB[w]; V1 += r.x; V2 += r.y; }
        float mn = V1 * (1.0f / 512.0f), vr = V2 * (1.0f / 512.0f) - mn * mn;
        float state = (x2v - mn) * rsqrtf(vr + 1e-5f) * sm->Gs[ch] + sm->Bes[ch];
        if (!p) sm->St[head * DM + ch] = state;
        float4 h1 = sm->B1v[ch];
        int base = head + 1; if (base >= MEMN) base -= MEMN;
        #pragma unroll
        for (int m = 0; m < MEMN - 1; ++m) {
          int slot = base + m; if (slot >= MEMN) slot -= MEMN;
          float tr = sm->St[slot * DM + ch];
          f16x4 wv = sm->W1h[m * DM + ch];
          h1.x += tr * (float)wv[0]; h1.y += tr * (float)wv[1];
          h1.z += tr * (float)wv[2]; h1.w += tr * (float)wv[3];
        }
        {
          f16x4 wv = sm->W1h[(MEMN - 1) * DM + ch];
          h1.x += state * (float)wv[0]; h1.y += state * (float)wv[1];
          h1.z += state * (float)wv[2]; h1.w += state * (float)wv[3];
        }
        float g0 = h1.x * sigm(h1.z), g1 = h1.y * sigm(h1.w);
        float4 w2v = sm->W2v[ch];
        float2 b2v = sm->B2v[ch];
        float o0 = g0 * w2v.x + g1 * w2v.z + b2v.x;
        float o1 = g0 * w2v.y + g1 * w2v.w + b2v.y;
        float act = o0 * sigm(o1);
        if (!p) sm->Act[ch] = act;
        float an = __shfl_xor(act, 2);
        if ((tid & 3) == 0) sm->Pre2[32 + (tid >> 2)] = pack2(act, an);
        head += 1; if (head >= MEMN) head = 0;
      }
      __syncthreads();  // B7
    }  // it

    // ---- S1: sync products + next-step Wb partials + store logits(t-1) ----
    {
      int pr = sm->Pair[tid];
      sm->Prod[tid] = sm->Act[pr >> 8] * sm->Act[pr & 255];
      if (tid < SYNCD - 512) {
        int pr2 = sm->Pair[512 + tid];
        sm->Prod[512 + tid] = sm->Act[pr2 >> 8] * sm->Act[pr2 & 255];
      }
      const float* X = sm->X2[(t + 1) & 1];
      float s = 0.f;
      #pragma unroll
      for (int e = 0; e < 8; ++e) s += X[kcK * 8 + e] * (float)wbr8[e];
      sm->PartK[kcK * 64 + jK] = s;
      if (t > 0 && tid < VOC) {
        float o = sm->Bh[tid];
        #pragma unroll
        for (int kc2 = 0; kc2 < 16; ++kc2) o += sm->PartH[kc2 * 15 + tid];
        P.out[((size_t)b * T_LEN + (t - 1)) * VOC + tid] = o;
      }
    }
    __syncthreads();  // B8

    // ---- S2: Wh partials + kv reduce/pack for t+1 ----
    if (tid < 240) {
      int kc = (tid * 4370) >> 16;
      int v = tid - kc * 15;
      float s = 0.f;
      #pragma unroll
      for (int e = 0; e < 33; ++e) {
        int pp = kc * 33 + e;
        s += sm->Prod[pp] * sm->WhL[pp * 15 + v];
      }
      sm->PartH[kc * 15 + v] = s;
    } else if (tid >= 256 && tid < 320) {
      int j = tid - 256;
      float kv = sm->Bb[j];
      #pragma unroll
      for (int kc = 0; kc < 8; ++kc) kv += sm->PartK[kc * 64 + j];
      kv = fmaxf(kv, 0.f);
      float kn = __shfl_xor(kv, 1);
      if ((j & 1) == 0) sm->Pre2[j >> 1] = pack2(kv, kn);
    }
    __syncthreads();  // B9
  }  // t

  if (tid < VOC) {
    float o = sm->Bh[tid];
    #pragma unroll
    for (int kc = 0; kc < 16; ++kc) o += sm->PartH[kc * 15 + tid];
    P.out[((size_t)b * T_LEN + (T_LEN - 1)) * VOC + tid] = o;
  }
}

extern "C" void kernel_launch(void* const* d_in, const int* in_sizes, int n_in,
                              void* d_out, int out_size, void* d_ws, size_t ws_size,
                              hipStream_t stream) {
  (void)n_in; (void)out_size; (void)ws_size;
  Params P;
  P.x   = (const float*)d_in[0];
  P.st0 = (const float*)d_in[1];
  P.ast0= (const float*)d_in[2];
  P.Wb  = (const float*)d_in[3];
  P.bb  = (const float*)d_in[4];
  P.Wf  = (const float*)d_in[5];
  P.bf  = (const float*)d_in[6];
  P.gf  = (const float*)d_in[7];
  P.bef = (const float*)d_in[8];
  P.Wd  = (const float*)d_in[9];
  P.bd  = (const float*)d_in[10];
  P.gd  = (const float*)d_in[11];
  P.bed = (const float*)d_in[12];
  P.Wu  = (const float*)d_in[13];
  P.bu  = (const float*)d_in[14];
  P.gu  = (const float*)d_in[15];
  P.beu = (const float*)d_in[16];
  P.gs  = (const float*)d_in[17];
  P.bes = (const float*)d_in[18];
  P.w1  = (const float*)d_in[19];
  P.b1  = (const float*)d_in[20];
  P.w2  = (const float*)d_in[21];
  P.b2  = (const float*)d_in[22];
  P.Wh  = (const float*)d_in[23];
  P.bh  = (const float*)d_in[24];
  P.out = (float*)d_out;

  f16* wf16 = (f16*)d_ws;
  hipLaunchKernelGGL(wf16_kernel, dim3(320), dim3(512), 0, stream, P.Wf, wf16);
  P.wf16 = wf16;

  int B = in_sizes[0] / (T_LEN * DI);
  hipLaunchKernelGGL(ctm_kernel, dim3(B), dim3(512), 0, stream, P);
}

// Round 9
// 12809.760 us; speedup vs baseline: 1.6846x; 1.4371x over previous
//
#include <hip/hip_runtime.h>
#include <math.h>

#define T_LEN 1500
#define DM 256
#define DI 64
#define MEMN 10
#define SYNCD 528
#define VOC 15

typedef _Float16 f16x2 __attribute__((ext_vector_type(2)));
typedef _Float16 f16x8 __attribute__((ext_vector_type(8)));

#define FDOT2(a, b, c) __builtin_amdgcn_fdot2((a), (b), (c), false)

static __device__ __forceinline__ float dot8(f16x8 w, f16x8 q, float acc) {
  acc = FDOT2(__builtin_shufflevector(w, w, 0, 1), __builtin_shufflevector(q, q, 0, 1), acc);
  acc = FDOT2(__builtin_shufflevector(w, w, 2, 3), __builtin_shufflevector(q, q, 2, 3), acc);
  acc = FDOT2(__builtin_shufflevector(w, w, 4, 5), __builtin_shufflevector(q, q, 4, 5), acc);
  acc = FDOT2(__builtin_shufflevector(w, w, 6, 7), __builtin_shufflevector(q, q, 6, 7), acc);
  return acc;
}
static __device__ __forceinline__ f16x2 pack2(float a, float b) {
  f16x2 r; r.x = (_Float16)a; r.y = (_Float16)b; return r;
}
static __device__ __forceinline__ float sigm(float x) { return 1.0f / (1.0f + __expf(-x)); }

// ---- DPP cross-lane (VALU-latency, replaces ds_bpermute shuffles) ----
// row_shr:N = 0x110|N, row_bcast15 = 0x142, row_bcast31 = 0x143, quad_perm = low byte
#define DPP_TERM(x, ctrl, rmask) \
  __int_as_float(__builtin_amdgcn_update_dpp(0, __float_as_int(x), (ctrl), (rmask), 0xF, true))
#define DPPADD(x, ctrl, rmask) (x) += DPP_TERM(x, ctrl, rmask)
// full 64-lane sum of a and b; result valid in lane 63 of each wave
#define WSUM2(a, b) do { \
  DPPADD(a, 0x111, 0xF); DPPADD(b, 0x111, 0xF); \
  DPPADD(a, 0x112, 0xF); DPPADD(b, 0x112, 0xF); \
  DPPADD(a, 0x114, 0xF); DPPADD(b, 0x114, 0xF); \
  DPPADD(a, 0x118, 0xF); DPPADD(b, 0x118, 0xF); \
  DPPADD(a, 0x142, 0xA); DPPADD(b, 0x142, 0xA); \
  DPPADD(a, 0x143, 0xC); DPPADD(b, 0x143, 0xC); \
} while (0)
static __device__ __forceinline__ float readlane_f(float x, int l) {
  return __int_as_float(__builtin_amdgcn_readlane(__float_as_int(x), l));
}

struct Params {
  const float *x, *st0, *ast0, *Wb, *bb, *Wf, *bf, *gf, *bef,
              *Wd, *bd, *gd, *bed, *Wu, *bu, *gu, *beu, *gs, *bes,
              *w1, *b1, *w2, *b2, *Wh, *bh;
  float* out;
};

struct Smem {
  float4 W1v[MEMN * DM];
  float4 W2v[DM];
  float4 B1v[DM];
  float2 B2v[DM];
  float Bf[2 * DM];
  float Bu[2 * DM];
  float Bd[32];
  float Gf[DM], Bef[DM], Gu[DM], Beu[DM], Gs[DM], Bes[DM];
  float Gd[16], Bed[16];
  float Bh[16];
  float Bb[DI];
  __attribute__((aligned(16))) float St[MEMN * DM];
  __attribute__((aligned(16))) float H0[DM];
  float Act[DM];
  __attribute__((aligned(16))) float D1[16];
  float X2[2][DI];
  __attribute__((aligned(16))) f16x2 Pre2[160];
  float PartD[16 * 33];
  float PartK[512];
  float PartH[240];
  float2 RedAB[8];
  float2 Red2AB[8];
  float Prod[SYNCD];
  float WhL[SYNCD * VOC];
  int Pair[SYNCD];
};

#define FOR20(X) X(0) X(1) X(2) X(3) X(4) X(5) X(6) X(7) X(8) X(9) \
                 X(10) X(11) X(12) X(13) X(14) X(15) X(16) X(17) X(18) X(19)

#define DECLW(i) f16x8 wa##i, wb##i;
#define LOADW(i) { const float* Wc = P.Wf + (size_t)(p160 + (i) * 8) * 512 + ch; \
  f16x8 ta, tb; \
  _Pragma("unroll") for (int e = 0; e < 8; ++e) { \
    ta[e] = (_Float16)Wc[e * 512]; tb[e] = (_Float16)Wc[e * 512 + 256]; } \
  wa##i = ta; wb##i = tb; }
#define DOT0(i) { f16x8 q = pr8[i]; aA0 = dot8(wa##i, q, aA0); aB0 = dot8(wb##i, q, aB0); }
#define DOT1(i) { f16x8 q = pr8[i]; aA1 = dot8(wa##i, q, aA1); aB1 = dot8(wb##i, q, aB1); }
#define DOTSEQ DOT0(0) DOT1(1) DOT0(2) DOT1(3) DOT0(4) DOT1(5) DOT0(6) DOT1(7) DOT0(8) DOT1(9) \
               DOT0(10) DOT1(11) DOT0(12) DOT1(13) DOT0(14) DOT1(15) DOT0(16) DOT1(17) DOT0(18) DOT1(19)

__global__ __launch_bounds__(512) __attribute__((amdgpu_waves_per_eu(2, 2)))
void ctm_kernel(Params P) {
  const int tid = threadIdx.x;
  const int b = blockIdx.x;
  __shared__ Smem sm_s;
  Smem* sm = &sm_s;

  // ---------------- LDS preload (once) ----------------
  for (int i = tid; i < MEMN * DM; i += 512) sm->W1v[i] = ((const float4*)P.w1)[i];
  if (tid < DM) {
    float2 a = ((const float2*)P.w2)[tid];
    float2 c = ((const float2*)P.w2)[DM + tid];
    float4 w; w.x = a.x; w.y = a.y; w.z = c.x; w.w = c.y;
    sm->W2v[tid] = w;
    sm->B1v[tid] = ((const float4*)P.b1)[tid];
    sm->B2v[tid] = ((const float2*)P.b2)[tid];
    sm->Gf[tid] = P.gf[tid]; sm->Bef[tid] = P.bef[tid];
    sm->Gu[tid] = P.gu[tid]; sm->Beu[tid] = P.beu[tid];
    sm->Gs[tid] = P.gs[tid]; sm->Bes[tid] = P.bes[tid];
  }
  sm->Bf[tid] = P.bf[tid];
  sm->Bu[tid] = P.bu[tid];
  if (tid < 32) sm->Bd[tid] = P.bd[tid];
  if (tid < 16) { sm->Gd[tid] = P.gd[tid]; sm->Bed[tid] = P.bed[tid]; }
  if (tid < VOC) sm->Bh[tid] = P.bh[tid];
  if (tid < DI) sm->Bb[tid] = P.bb[tid];
  for (int i = tid; i < MEMN * DM; i += 512) {
    int m = i >> 8, d = i & 255;
    sm->St[m * DM + d] = P.st0[d * MEMN + m];
  }
  if (tid < DI) sm->X2[0][tid] = P.x[(size_t)b * T_LEN * DI + tid];
  for (int i = tid; i < SYNCD * VOC; i += 512) sm->WhL[i] = P.Wh[i];
  for (int pp = tid; pp < SYNCD; pp += 512) {
    int i = 0, cum = 0;
    while (pp >= cum + (32 - i)) { cum += 32 - i; ++i; }
    sm->Pair[pp] = (i << 8) | (i + (pp - cum));
  }

  // ---------------- register-resident weights ----------------
  const int p = tid & 1;
  const int ch = tid >> 1;
  const int p160 = p * 160;
  FOR20(DECLW)
  FOR20(LOADW)
  const int jD = tid & 31, kcD = tid >> 5;
  float wd[16];
  #pragma unroll
  for (int q = 0; q < 16; ++q) wd[q] = P.Wd[(kcD * 16 + q) * 32 + jD];
  float wua[8], wub[8];
  #pragma unroll
  for (int q = 0; q < 8; ++q) {
    wua[q] = P.Wu[(p * 8 + q) * 512 + ch];
    wub[q] = P.Wu[(p * 8 + q) * 512 + ch + 256];
  }
  const int jK = tid & 63, kcK = tid >> 6;
  float wbr[8];
  #pragma unroll
  for (int q = 0; q < 8; ++q) wbr[q] = P.Wb[(kcK * 8 + q) * 64 + jK];

  __syncthreads();

  // ---------------- prologue: kv(t=0) + initial act pack ----------------
  {
    float s = 0.f;
    #pragma unroll
    for (int q = 0; q < 8; ++q) s += sm->X2[0][kcK * 8 + q] * wbr[q];
    sm->PartK[kcK * 64 + jK] = s;
    if ((tid & 3) == 0) {
      int e = tid >> 2;
      float a0 = P.ast0[(2 * e) * MEMN + (MEMN - 1)];
      float a1 = P.ast0[(2 * e + 1) * MEMN + (MEMN - 1)];
      sm->Pre2[32 + e] = pack2(a0, a1);
    }
  }
  __syncthreads();
  if (tid >= 256 && tid < 320) {
    int j = tid - 256;
    float kv = sm->Bb[j];
    #pragma unroll
    for (int kc = 0; kc < 8; ++kc) kv += sm->PartK[kc * 64 + j];
    kv = fmaxf(kv, 0.f);
    float kn = DPP_TERM(kv, 0xB1, 0xF);             // lane^1 value
    if ((j & 1) == 0) sm->Pre2[j >> 1] = pack2(kv, kn);
  }
  __syncthreads();

  int head = 0;
  for (int t = 0; t < T_LEN; ++t) {
    float xr = 0.f;
    if (tid < DI && t + 1 < T_LEN) xr = P.x[((size_t)b * T_LEN + (t + 1)) * DI + tid];

    for (int it = 0; it < 2; ++it) {
      // ---- P1: Wf GEMV + GLU + DPP wave-reduce ----
      if (it == 1 && tid < DI) sm->X2[(t + 1) & 1][tid] = xr;
      float aA0 = 0.f, aA1 = 0.f, aB0 = 0.f, aB1 = 0.f;
      const f16x8* pr8 = (const f16x8*)(sm->Pre2 + p * 80);
      DOTSEQ
      float av = aA0 + aA1, bv = aB0 + aB1;
      DPPADD(av, 0xB1, 0xF);                        // += lane^1
      DPPADD(bv, 0xB1, 0xF);
      av += sm->Bf[ch]; bv += sm->Bf[DM + ch];
      float g = av * sigm(bv);
      float s1 = g, s2 = g * g;
      WSUM2(s1, s2);                                // lane 63 holds wave sums
      if ((tid & 63) == 63) { float2 r; r.x = s1; r.y = s2; sm->RedAB[tid >> 6] = r; }
      __syncthreads();  // B1

      // ---- P2: h0 = LN(g) ----
      float S1 = 0.f, S2 = 0.f;
      #pragma unroll
      for (int w = 0; w < 8; ++w) { float2 r = sm->RedAB[w]; S1 += r.x; S2 += r.y; }
      float mean = S1 * (1.0f / 512.0f);
      float var = S2 * (1.0f / 512.0f) - mean * mean;
      float h0v = (g - mean) * rsqrtf(var + 1e-5f) * sm->Gf[ch] + sm->Bef[ch];
      if (!p) sm->H0[ch] = h0v;
      __syncthreads();  // B2

      // ---- P3: Wd partials ----
      {
        float s = 0.f;
        #pragma unroll
        for (int qq = 0; qq < 4; ++qq) {
          float4 hv = ((const float4*)sm->H0)[kcD * 4 + qq];
          s += hv.x * wd[qq * 4 + 0] + hv.y * wd[qq * 4 + 1]
             + hv.z * wd[qq * 4 + 2] + hv.w * wd[qq * 4 + 3];
        }
        sm->PartD[kcD * 33 + jD] = s;
      }
      __syncthreads();  // B3

      // ---- P4: d1 = LN(GLU(Wd out)) (wave 0, lanes 0-31) ----
      if (tid < 32) {
        int j = tid & 15;
        float s = 0.f;
        #pragma unroll
        for (int kc = 0; kc < 16; ++kc) s += sm->PartD[kc * 33 + (tid >> 4) * 16 + j];
        float oth = __shfl_xor(s, 16);
        float gg = (s + sm->Bd[j]) * sigm(oth + sm->Bd[16 + j]);
        float t1 = gg, t2 = gg * gg;
        DPPADD(t1, 0x111, 0xF); DPPADD(t2, 0x111, 0xF);
        DPPADD(t1, 0x112, 0xF); DPPADD(t2, 0x112, 0xF);
        DPPADD(t1, 0x114, 0xF); DPPADD(t2, 0x114, 0xF);
        DPPADD(t1, 0x118, 0xF); DPPADD(t2, 0x118, 0xF);   // lane 15 = sum of lanes 0..15
        float T1 = readlane_f(t1, 15), T2 = readlane_f(t2, 15);
        float mn = T1 * (1.0f / 16.0f), vr = T2 * (1.0f / 16.0f) - mn * mn;
        float d1 = (gg - mn) * rsqrtf(vr + 1e-5f) * sm->Gd[j] + sm->Bed[j];
        if (tid < 16) sm->D1[j] = d1;
      }
      __syncthreads();  // B4

      // ---- P5: Wu + GLU + DPP wave-reduce ----
      float gu;
      {
        const float4* d4 = (const float4*)sm->D1;
        float4 dl = d4[p * 2], dh = d4[p * 2 + 1];
        float ua = dl.x * wua[0] + dl.y * wua[1] + dl.z * wua[2] + dl.w * wua[3]
                 + dh.x * wua[4] + dh.y * wua[5] + dh.z * wua[6] + dh.w * wua[7];
        float ub = dl.x * wub[0] + dl.y * wub[1] + dl.z * wub[2] + dl.w * wub[3]
                 + dh.x * wub[4] + dh.y * wub[5] + dh.z * wub[6] + dh.w * wub[7];
        DPPADD(ua, 0xB1, 0xF);
        DPPADD(ub, 0xB1, 0xF);
        ua += sm->Bu[ch]; ub += sm->Bu[DM + ch];
        gu = ua * sigm(ub);
        float t1 = gu, t2 = gu * gu;
        WSUM2(t1, t2);
        if ((tid & 63) == 63) { float2 r; r.x = t1; r.y = t2; sm->RedAB[tid >> 6] = r; }
      }
      __syncthreads();  // B5

      // ---- P6: u0 = LN(gu); x2 = u0 + h0; DPP reduce for state-LN ----
      float x2v;
      {
        float U1 = 0.f, U2 = 0.f;
        #pragma unroll
        for (int w = 0; w < 8; ++w) { float2 r = sm->RedAB[w]; U1 += r.x; U2 += r.y; }
        float mn = U1 * (1.0f / 512.0f), vr = U2 * (1.0f / 512.0f) - mn * mn;
        float u0 = (gu - mn) * rsqrtf(vr + 1e-5f) * sm->Gu[ch] + sm->Beu[ch];
        x2v = u0 + h0v;
        float t1 = x2v, t2 = x2v * x2v;
        WSUM2(t1, t2);
        if ((tid & 63) == 63) { float2 r; r.x = t1; r.y = t2; sm->Red2AB[tid >> 6] = r; }
      }
      __syncthreads();  // B6

      // ---- P7: state = LN(x2); trace; nlm -> act; pack pre ----
      {
        float V1 = 0.f, V2 = 0.f;
        #pragma unroll
        for (int w = 0; w < 8; ++w) { float2 r = sm->Red2AB[w]; V1 += r.x; V2 += r.y; }
        float mn = V1 * (1.0f / 512.0f), vr = V2 * (1.0f / 512.0f) - mn * mn;
        float state = (x2v - mn) * rsqrtf(vr + 1e-5f) * sm->Gs[ch] + sm->Bes[ch];
        if (!p) sm->St[head * DM + ch] = state;
        float4 h1 = sm->B1v[ch];
        int base = head + 1; if (base >= MEMN) base -= MEMN;
        #pragma unroll
        for (int m = 0; m < MEMN - 1; ++m) {
          int slot = base + m; if (slot >= MEMN) slot -= MEMN;
          float tr = sm->St[slot * DM + ch];
          float4 wv = sm->W1v[m * DM + ch];
          h1.x += tr * wv.x; h1.y += tr * wv.y; h1.z += tr * wv.z; h1.w += tr * wv.w;
        }
        {
          float4 wv = sm->W1v[(MEMN - 1) * DM + ch];
          h1.x += state * wv.x; h1.y += state * wv.y; h1.z += state * wv.z; h1.w += state * wv.w;
        }
        float g0 = h1.x * sigm(h1.z), g1 = h1.y * sigm(h1.w);
        float4 w2v = sm->W2v[ch];
        float2 b2v = sm->B2v[ch];
        float o0 = g0 * w2v.x + g1 * w2v.z + b2v.x;
        float o1 = g0 * w2v.y + g1 * w2v.w + b2v.y;
        float act = o0 * sigm(o1);
        if (!p) sm->Act[ch] = act;
        float an = DPP_TERM(act, 0x4E, 0xF);       // lane^2 value (quad_perm [2,3,0,1])
        if ((tid & 3) == 0) sm->Pre2[32 + (tid >> 2)] = pack2(act, an);
        head += 1; if (head >= MEMN) head = 0;
      }
      __syncthreads();  // B7
    }  // it

    // ---- S1: sync products + next-step Wb partials + store logits(t-1) ----
    {
      int pr = sm->Pair[tid];
      sm->Prod[tid] = sm->Act[pr >> 8] * sm->Act[pr & 255];
      if (tid < SYNCD - 512) {
        int pr2 = sm->Pair[512 + tid];
        sm->Prod[512 + tid] = sm->Act[pr2 >> 8] * sm->Act[pr2 & 255];
      }
      const float* X = sm->X2[(t + 1) & 1];
      float s = 0.f;
      #pragma unroll
      for (int q = 0; q < 8; ++q) s += X[kcK * 8 + q] * wbr[q];
      sm->PartK[kcK * 64 + jK] = s;
      if (t > 0 && tid < VOC) {
        float o = sm->Bh[tid];
        #pragma unroll
        for (int kc2 = 0; kc2 < 16; ++kc2) o += sm->PartH[kc2 * 15 + tid];
        P.out[((size_t)b * T_LEN + (t - 1)) * VOC + tid] = o;
      }
    }
    __syncthreads();  // B8

    // ---- S2: Wh partials + kv reduce/pack for t+1 ----
    if (tid < 240) {
      int kc = (tid * 4370) >> 16;
      int v = tid - kc * 15;
      float s = 0.f;
      #pragma unroll
      for (int q = 0; q < 33; ++q) {
        int pp = kc * 33 + q;
        s += sm->Prod[pp] * sm->WhL[pp * 15 + v];
      }
      sm->PartH[kc * 15 + v] = s;
    } else if (tid >= 256 && tid < 320) {
      int j = tid - 256;
      float kv = sm->Bb[j];
      #pragma unroll
      for (int kc = 0; kc < 8; ++kc) kv += sm->PartK[kc * 64 + j];
      kv = fmaxf(kv, 0.f);
      float kn = DPP_TERM(kv, 0xB1, 0xF);
      if ((j & 1) == 0) sm->Pre2[j >> 1] = pack2(kv, kn);
    }
    __syncthreads();  // B9
  }  // t

  if (tid < VOC) {
    float o = sm->Bh[tid];
    #pragma unroll
    for (int kc = 0; kc < 16; ++kc) o += sm->PartH[kc * 15 + tid];
    P.out[((size_t)b * T_LEN + (T_LEN - 1)) * VOC + tid] = o;
  }
}

extern "C" void kernel_launch(void* const* d_in, const int* in_sizes, int n_in,
                              void* d_out, int out_size, void* d_ws, size_t ws_size,
                              hipStream_t stream) {
  (void)d_ws; (void)ws_size; (void)n_in; (void)out_size;
  Params P;
  P.x   = (const float*)d_in[0];
  P.st0 = (const float*)d_in[1];
  P.ast0= (const float*)d_in[2];
  P.Wb  = (const float*)d_in[3];
  P.bb  = (const float*)d_in[4];
  P.Wf  = (const float*)d_in[5];
  P.bf  = (const float*)d_in[6];
  P.gf  = (const float*)d_in[7];
  P.bef = (const float*)d_in[8];
  P.Wd  = (const float*)d_in[9];
  P.bd  = (const float*)d_in[10];
  P.gd  = (const float*)d_in[11];
  P.bed = (const float*)d_in[12];
  P.Wu  = (const float*)d_in[13];
  P.bu  = (const float*)d_in[14];
  P.gu  = (const float*)d_in[15];
  P.beu = (const float*)d_in[16];
  P.gs  = (const float*)d_in[17];
  P.bes = (const float*)d_in[18];
  P.w1  = (const float*)d_in[19];
  P.b1  = (const float*)d_in[20];
  P.w2  = (const float*)d_in[21];
  P.b2  = (const float*)d_in[22];
  P.Wh  = (const float*)d_in[23];
  P.bh  = (const float*)d_in[24];
  P.out = (float*)d_out;

  int B = in_sizes[0] / (T_LEN * DI);
  hipLaunchKernelGGL(ctm_kernel, dim3(B), dim3(512), 0, stream, P);
}